// Round 1
// baseline (530.767 us; speedup 1.0000x reference)
//
#include <hip/hip_runtime.h>
#include <cmath>
#include <complex>
#include <vector>
#include <algorithm>
#include <cstring>

// ---------------------------------------------------------------------------
// AtomCenteredTensorMomentDescriptor
// out[e, k3, f] = sum_paths R1[l1][f]*R2[l2][f] * P[e][slot(path,k3)]
//   where R{1,2}[l][f] = sum_k radcut[k]*W{1,2}[l][k][f]   (rank-1 factorization
//   of basis = Y (x) radcut), and P[slot] = sum_{ij} CG[i,j,k3]*Y_i*Y_j is
//   f-independent (computed once per edge, cooperatively, into LDS).
// Write-bound: 419 MB output, floor ~67us @ 6.3 TB/s.
// ---------------------------------------------------------------------------

#define MAXNNZ 4096

struct CGTab {
  int   rowPtr[136];   // CSR over 135 P-slots
  int   ij[MAXNNZ];    // packed iGlob | (jGlob<<8), indices into Y[16]
  float co[MAXNNZ];    // CG coefficient
};

__device__ CGTab d_tab;

// ---------------- host-side CG construction (exact port of reference) -------

static double factd(int n) { double f = 1.0; for (int i = 2; i <= n; ++i) f *= (double)i; return f; }

static void cg_complex(int j1, int j2, int j3, std::vector<double>& C) {
  int d2 = 2 * j2 + 1, d3 = 2 * j3 + 1;
  C.assign((2 * j1 + 1) * d2 * d3, 0.0);
  for (int m1 = -j1; m1 <= j1; ++m1)
    for (int m2 = -j2; m2 <= j2; ++m2) {
      int m3 = m1 + m2;
      if (m3 < -j3 || m3 > j3) continue;
      double pref = std::sqrt((2 * j3 + 1) * factd(j1 + j2 - j3) * factd(j1 - j2 + j3) *
                              factd(-j1 + j2 + j3) / factd(j1 + j2 + j3 + 1));
      pref *= std::sqrt(factd(j1 + m1) * factd(j1 - m1) * factd(j2 + m2) *
                        factd(j2 - m2) * factd(j3 + m3) * factd(j3 - m3));
      int kmin = std::max(0, std::max(j2 - j3 - m1, j1 - j3 + m2));
      int kmax = std::min(j1 + j2 - j3, std::min(j1 - m1, j2 + m2));
      double s = 0.0;
      for (int k = kmin; k <= kmax; ++k) {
        s += ((k & 1) ? -1.0 : 1.0) /
             (factd(k) * factd(j1 + j2 - j3 - k) * factd(j1 - m1 - k) *
              factd(j2 + m2 - k) * factd(j3 - j2 + m1 + k) * factd(j3 - j1 - m2 + k));
      }
      C[((m1 + j1) * d2 + (m2 + j2)) * d3 + (m3 + j3)] = pref * s;
    }
}

static void umat(int l, std::vector<std::complex<double>>& U) {
  int d = 2 * l + 1;
  U.assign(d * d, std::complex<double>(0, 0));
  U[l * d + l] = 1.0;
  const double is2 = 1.0 / std::sqrt(2.0);
  for (int m = 1; m <= l; ++m) {
    double sg = (m & 1) ? -1.0 : 1.0;
    U[(l + m) * d + (l + m)] = sg * is2;
    U[(l + m) * d + (l - m)] = is2;
    U[(l - m) * d + (l + m)] = std::complex<double>(0, -sg * is2);
    U[(l - m) * d + (l - m)] = std::complex<double>(0, is2);
  }
}

static void real_cg(int l1, int l2, int l3, std::vector<double>& R) {
  std::vector<double> Cc;
  cg_complex(l1, l2, l3, Cc);
  std::vector<std::complex<double>> U1, U2, U3;
  umat(l1, U1); umat(l2, U2); umat(l3, U3);
  int d1 = 2 * l1 + 1, d2 = 2 * l2 + 1, d3 = 2 * l3 + 1;
  R.assign(d1 * d2 * d3, 0.0);
  for (int a = 0; a < d1; ++a)
    for (int b = 0; b < d2; ++b)
      for (int c = 0; c < d3; ++c) {
        std::complex<double> s(0, 0);
        for (int i = 0; i < d1; ++i)
          for (int j = 0; j < d2; ++j) {
            int k = (i - l1) + (j - l2) + l3;  // m3 = m1 + m2 selection rule
            if (k < 0 || k >= d3) continue;
            double cc = Cc[(i * d2 + j) * d3 + k];
            if (cc == 0.0) continue;
            s += U1[a * d1 + i] * U2[b * d2 + j] * std::conj(U3[c * d3 + k]) * cc;
          }
        R[(a * d2 + b) * d3 + c] = s.real();
      }
}

static void build_tab(CGTab& T) {
  static const int off_in[5] = {0, 1, 4, 9, 16};
  int nnz = 0, slot = 0;
  std::vector<double> R;
  for (int l1 = 0; l1 <= 3; ++l1)
    for (int l2 = 0; l2 <= 3; ++l2)
      for (int l3 = 0; l3 <= 4; ++l3) {
        if (!(std::abs(l1 - l2) <= l3 && l3 <= l1 + l2 && ((l1 + l2 + l3) % 2 == 0))) continue;
        real_cg(l1, l2, l3, R);
        int d2 = 2 * l2 + 1, d3 = 2 * l3 + 1;
        for (int c = 0; c < d3; ++c) {
          T.rowPtr[slot] = nnz;
          for (int a = 0; a < 2 * l1 + 1; ++a)
            for (int b = 0; b < d2; ++b) {
              double v = R[(a * d2 + b) * d3 + c];
              if (std::fabs(v) > 1e-8 && nnz < MAXNNZ) {
                T.ij[nnz] = (off_in[l1] + a) | ((off_in[l2] + b) << 8);
                T.co[nnz] = (float)v;
                ++nnz;
              }
            }
          ++slot;
        }
      }
  T.rowPtr[slot] = nnz;  // slot == 135
}

// ---------------- device kernel --------------------------------------------

#define OUT_OFF(l3) ((l3) == 0 ? 0 : ((l3) == 1 ? 1 : ((l3) == 2 ? 4 : ((l3) == 3 ? 9 : 16))))

#define PATH(l1, l2, l3, sb)                                        \
  {                                                                 \
    const float t = R1v[l1] * R2v[l2];                              \
    _Pragma("unroll")                                               \
    for (int k = 0; k < 2 * (l3) + 1; ++k)                          \
      o[OUT_OFF(l3) + k] += t * Pl[(sb) + k];                       \
  }

__global__ __launch_bounds__(256) void atmd_kernel(
    const float* __restrict__ disp, const float* __restrict__ W1,
    const float* __restrict__ W2, float* __restrict__ out, int nE) {
  __shared__ float Ysh[4][16];
  __shared__ float P[4][136];

  const int tid = threadIdx.x;
  const int eL = tid >> 6;       // local edge (one wave per edge)
  const int f = tid & 63;        // feature lane
  const int e = blockIdx.x * 4 + eL;
  const int ec = e < nE ? e : nE - 1;  // clamp for loads; stores guarded

  // ---- per-edge geometry (all lanes; trivially cheap) ----
  const float dx = disp[3 * ec + 0], dy = disp[3 * ec + 1], dz = disp[3 * ec + 2];
  const float r = sqrtf(dx * dx + dy * dy + dz * dz + 1e-12f);
  const float rinv = 1.0f / r;
  const float x = dx * rinv, y = dy * rinv, z = dz * rinv;
  const float x2 = x * x, y2 = y * y, z2 = z * z;

  // radial * cutoff
  const float s = r * 0.2f;       // r / CUTOFF
  const float s2 = s * s;
  const float cut = (s2 < 1.0f) ? expf(1.0f - 1.0f / (1.0f - s2)) : 0.0f;
  float radcut[8];
  const float PIF = 3.14159265358979323846f;
#pragma unroll
  for (int k = 0; k < 8; ++k) {
    float px = PIF * (float)(k + 1) * s;    // pi * n * r/CUTOFF
    radcut[k] = cut * (sinf(px) / px);      // normalized sinc * cutoff
  }

  // spherical harmonics l=0..3 (only consumed via the lane-0 LDS write)
  if (f == 0) {
    float* q = &Ysh[eL][0];
    q[0]  = 0.28209479177387814f;
    q[1]  = 0.4886025119029199f * y;
    q[2]  = 0.4886025119029199f * z;
    q[3]  = 0.4886025119029199f * x;
    q[4]  = 1.0925484305920792f * x * y;
    q[5]  = 1.0925484305920792f * y * z;
    q[6]  = 0.31539156525252005f * (3.0f * z2 - 1.0f);
    q[7]  = 1.0925484305920792f * x * z;
    q[8]  = 0.5462742152960396f * (x2 - y2);
    q[9]  = 0.5900435899266435f * y * (3.0f * x2 - y2);
    q[10] = 2.890611442640554f * x * y * z;
    q[11] = 0.4570457994644658f * y * (5.0f * z2 - 1.0f);
    q[12] = 0.3731763325901154f * z * (5.0f * z2 - 3.0f);
    q[13] = 0.4570457994644658f * x * (5.0f * z2 - 1.0f);
    q[14] = 1.445305721320277f * z * (x2 - y2);
    q[15] = 0.5900435899266435f * x * (x2 - 3.0f * y2);
  }

  // ---- per-(edge,f) radial projections: R{1,2}[l][f] ----
  float R1v[4], R2v[4];
#pragma unroll
  for (int l = 0; l < 4; ++l) {
    float a = 0.f, b = 0.f;
#pragma unroll
    for (int k = 0; k < 8; ++k) {
      const float rc = radcut[k];
      a += rc * W1[(l * 8 + k) * 64 + f];
      b += rc * W2[(l * 8 + k) * 64 + f];
    }
    R1v[l] = a;
    R2v[l] = b;
  }

  __syncthreads();  // Ysh visible

  // ---- cooperative P[slot] = sum CG * Y_i * Y_j  (f-independent) ----
  const float* Ye = &Ysh[eL][0];
  for (int sIdx = f; sIdx < 135; sIdx += 64) {
    const int b0 = d_tab.rowPtr[sIdx], b1 = d_tab.rowPtr[sIdx + 1];
    float acc = 0.f;
    for (int t = b0; t < b1; ++t) {
      const int p = d_tab.ij[t];
      acc += d_tab.co[t] * Ye[p & 255] * Ye[(p >> 8) & 255];
    }
    P[eL][sIdx] = acc;
  }
  __syncthreads();

  // ---- accumulate the 25 output components ----
  const float* Pl = &P[eL][0];
  float o[25];
#pragma unroll
  for (int k = 0; k < 25; ++k) o[k] = 0.f;

  // (l1, l2, l3, slotBase) — parity-even triangle paths, reference order
  PATH(0, 0, 0, 0)   PATH(0, 1, 1, 1)   PATH(0, 2, 2, 4)   PATH(0, 3, 3, 9)
  PATH(1, 0, 1, 16)  PATH(1, 1, 0, 19)  PATH(1, 1, 2, 20)  PATH(1, 2, 1, 25)
  PATH(1, 2, 3, 28)  PATH(1, 3, 2, 35)  PATH(1, 3, 4, 40)
  PATH(2, 0, 2, 49)  PATH(2, 1, 1, 54)  PATH(2, 1, 3, 57)  PATH(2, 2, 0, 64)
  PATH(2, 2, 2, 65)  PATH(2, 2, 4, 70)  PATH(2, 3, 1, 79)  PATH(2, 3, 3, 82)
  PATH(3, 0, 3, 89)  PATH(3, 1, 2, 96)  PATH(3, 1, 4, 101) PATH(3, 2, 1, 110)
  PATH(3, 2, 3, 113) PATH(3, 3, 0, 120) PATH(3, 3, 2, 121) PATH(3, 3, 4, 126)

  // ---- store: (e, k3, f), coalesced over f ----
  if (e < nE) {
    const size_t obase = (size_t)e * 1600 + f;  // 25*64
#pragma unroll
    for (int k3 = 0; k3 < 25; ++k3) out[obase + (size_t)k3 * 64] = o[k3];
  }
}

// ---------------- launch ----------------------------------------------------

extern "C" void kernel_launch(void* const* d_in, const int* in_sizes, int n_in,
                              void* d_out, int out_size, void* d_ws, size_t ws_size,
                              hipStream_t stream) {
  const float* disp = (const float*)d_in[0];
  const float* W1 = (const float*)d_in[1];
  const float* W2 = (const float*)d_in[2];
  float* out = (float*)d_out;

  const int nE = in_sizes[0] / 3;  // 4096*16 = 65536 edges

  // Deterministic host-side CG table, rebuilt every call (host work only runs
  // at capture/correctness time; the H2D copy is a captured graph node so it
  // replays before every timed launch, surviving the d_ws/d_out re-poison).
  static CGTab h_tab;
  build_tab(h_tab);
  void* sym = nullptr;
  (void)hipGetSymbolAddress(&sym, HIP_SYMBOL(d_tab));
  (void)hipMemcpyAsync(sym, &h_tab, sizeof(CGTab), hipMemcpyHostToDevice, stream);

  const int blocks = (nE + 3) / 4;
  atmd_kernel<<<blocks, 256, 0, stream>>>(disp, W1, W2, out, nE);
}